// Round 4
// baseline (275.351 us; speedup 1.0000x reference)
//
#include <hip/hip_runtime.h>
#include <hip/hip_bf16.h>
#include <stdint.h>

// ---------------- problem constants ----------------
#define BB 2
#define TT 2048
#define DD 2048
#define HH 16
#define KVH 8
#define HDIM 128
#define BT (BB*TT)            // 4096
#define NQKV (HH*HDIM + 2*KVH*HDIM) // 4096
#define TQ (TT/128)           // 16 q-blocks of 128 rows
#define ATT_SCALE 0.08838834764831845f
#define RMS_EPS 1e-6f

typedef __bf16 bf16;
typedef __bf16 bf16x8 __attribute__((ext_vector_type(8)));
typedef __bf16 bf16x4 __attribute__((ext_vector_type(4)));
typedef float  f32x4  __attribute__((ext_vector_type(4)));

// async global->LDS, 16B per lane. LDS dest = wave-uniform base + lane*16.
__device__ __forceinline__ void gl_lds16(const void* g, const void* l) {
  __builtin_amdgcn_global_load_lds(
      (const __attribute__((address_space(1))) void*)(uintptr_t)g,
      (__attribute__((address_space(3))) void*)(uint32_t)(uintptr_t)l,
      16, 0, 0);
}

// ---------------- elementwise f32 -> bf16 cast ----------------
__global__ __launch_bounds__(256) void cast_bf16_k(const float* __restrict__ in,
                                                   bf16* __restrict__ out, int n4) {
  int i = blockIdx.x * blockDim.x + threadIdx.x;
  int stride = gridDim.x * blockDim.x;
  for (; i < n4; i += stride) {
    float4 v = ((const float4*)in)[i];
    bf16x4 o = { (bf16)v.x, (bf16)v.y, (bf16)v.z, (bf16)v.w };
    *(bf16x4*)(out + (size_t)i * 4) = o;
  }
}

// ---------------- f32 (R x C) -> bf16 (C x R) transpose-cast ----------------
__global__ __launch_bounds__(256) void transpose_cast_k(const float* __restrict__ in,
                                                        bf16* __restrict__ out,
                                                        int R, int C) {
  __shared__ float tile[32][33];
  int tx = threadIdx.x & 31, ty = threadIdx.x >> 5;
  int c0 = blockIdx.x * 32, r0 = blockIdx.y * 32;
#pragma unroll
  for (int i = 0; i < 4; ++i)
    tile[ty + 8*i][tx] = in[(size_t)(r0 + ty + 8*i) * C + c0 + tx];
  __syncthreads();
#pragma unroll
  for (int i = 0; i < 4; ++i)
    out[(size_t)(c0 + ty + 8*i) * R + r0 + tx] = (bf16)tile[tx][ty + 8*i];
}

// ---------------- bf16 V transpose: (B,T,KV,HD) -> (B,KV,HD,T) ----------------
__global__ __launch_bounds__(256) void transpose_v_k(const bf16* __restrict__ vb,
                                                     bf16* __restrict__ vbt) {
  __shared__ bf16 tile[32][33];
  int tx = threadIdx.x & 31, ty = threadIdx.x >> 5;
  int t0 = blockIdx.x * 32;
  int d0 = blockIdx.y * 32;
  int bk = blockIdx.z;                 // b*KV + kv
  int b = bk >> 3, kv = bk & 7;
#pragma unroll
  for (int i = 0; i < 4; ++i)
    tile[ty + 8*i][tx] = vb[(((size_t)(b*TT + t0 + ty + 8*i)) * KVH + kv) * HDIM + d0 + tx];
  __syncthreads();
#pragma unroll
  for (int i = 0; i < 4; ++i)
    vbt[(((size_t)bk) * HDIM + d0 + ty + 8*i) * TT + t0 + tx] = tile[tx][ty + 8*i];
}

// ---------------- GEMM C = A(MxK) * Bt(NxK)^T, m97 structure (128x128) ----------------
template <int OUT_F32>
__global__ __launch_bounds__(256, 2)
void gemm_bt_k(const bf16* __restrict__ A, const bf16* __restrict__ Bt,
               void* __restrict__ Cout, int M, int N, int K) {
  __shared__ bf16 As[128 * 32];
  __shared__ bf16 Bs[128 * 32];
  const int tid = threadIdx.x;
  const int lane = tid & 63, wid = tid >> 6;
  const int lr = lane & 15, lq = lane >> 4;
  const int bm = blockIdx.y * 128, bn = blockIdx.x * 128;
  const int wr = wid >> 1, wc = wid & 1;
  const bf16* Ab = A + (size_t)bm * K;
  const bf16* Bb = Bt + (size_t)bn * K;
  f32x4 acc[4][4] = {};
  for (int k0 = 0; k0 < K; k0 += 32) {
#pragma unroll
    for (int r = 0; r < 2; ++r) {
      int ch = r * 256 + tid;
      int row = ch >> 2, c8 = ch & 3;
      const bf16* lbase = As + (size_t)(r * 256 + wid * 64) * 8;
      gl_lds16(Ab + (size_t)row * K + k0 + c8 * 8, lbase);
      const bf16* lbase2 = Bs + (size_t)(r * 256 + wid * 64) * 8;
      gl_lds16(Bb + (size_t)row * K + k0 + c8 * 8, lbase2);
    }
    __syncthreads();
    bf16x8 af[4], bfv[4];
#pragma unroll
    for (int m = 0; m < 4; ++m)
      af[m] = *(const bf16x8*)&As[(wr * 64 + m * 16 + lr) * 32 + lq * 8];
#pragma unroll
    for (int n = 0; n < 4; ++n)
      bfv[n] = *(const bf16x8*)&Bs[(wc * 64 + n * 16 + lr) * 32 + lq * 8];
#pragma unroll
    for (int m = 0; m < 4; ++m)
#pragma unroll
      for (int n = 0; n < 4; ++n)
        acc[m][n] = __builtin_amdgcn_mfma_f32_16x16x32_bf16(af[m], bfv[n], acc[m][n], 0, 0, 0);
    __syncthreads();
  }
#pragma unroll
  for (int m = 0; m < 4; ++m)
#pragma unroll
    for (int n = 0; n < 4; ++n)
#pragma unroll
      for (int r = 0; r < 4; ++r) {
        int row = bm + wr * 64 + m * 16 + lq * 4 + r;
        int col = bn + wc * 64 + n * 16 + lr;
        if (OUT_F32) ((float*)Cout)[(size_t)row * N + col] = acc[m][n][r];
        else         ((bf16*)Cout)[(size_t)row * N + col] = (bf16)acc[m][n][r];
      }
}

// ---------------- GEMM 256x256, BK=64, 8-phase counted-vmcnt schedule ----------------
template <int OUT_F32>
__global__ __launch_bounds__(512, 2)
void gemm256_k(const bf16* __restrict__ A, const bf16* __restrict__ Bt,
               void* __restrict__ Cout, int M, int N, int K) {
  __shared__ bf16 S[2 * 2 * 2 * 128 * 64];   // 128 KiB
  const int tid = threadIdx.x, lane = tid & 63, wid = tid >> 6;
  const int lr = lane & 15, lq = lane >> 4;
  const int wrow = wid >> 1, wcol = wid & 1;

  // XCD-aware bijective swizzle of the flat block id (nwg % 8 == 0 here)
  const int nwg = gridDim.x;
  const int o = blockIdx.x;
  const int ns = (o & 7) * (nwg >> 3) + (o >> 3);
  const int GX = N >> 8;
  const int by = ns / GX, bx = ns % GX;

  const int NT = K >> 6;
  const bf16* Ab = A + (size_t)(by * 256) * K;
  const bf16* Bb = Bt + (size_t)(bx * 256) * K;

  const int srow = tid >> 3;
  const size_t soff = (size_t)srow * K + (((tid & 7) ^ (srow & 7)) * 8);
  const int ldst0 = wid * 512;

  auto STAGE = [&](int op, int h, int t_) {
    int tc = t_ < NT ? t_ : NT - 1;
    const bf16* src = (op ? Bb : Ab) + soff + (size_t)(h * 128) * K + tc * 64;
    bf16* dst = S + ((((((t_ & 1) << 1) | op) << 1) | h) << 13) + ldst0;
#pragma unroll
    for (int i = 0; i < 2; ++i)
      gl_lds16(src + (size_t)(i * 64) * K, dst + i * 4096);
  };

  bf16x8 af[2][2][2];   // [mh][m][ks]
  bf16x8 bfr[4][2];     // [n][ks]
  f32x4 acc[4][2][4] = {};  // [quad][m][n]

  auto LOAD_A = [&](int buf) {
#pragma unroll
    for (int mh = 0; mh < 2; ++mh) {
      const bf16* base = S + (((buf << 2) | mh) << 13);
#pragma unroll
      for (int m = 0; m < 2; ++m) {
        int ra = wrow * 32 + m * 16 + lr;
#pragma unroll
        for (int ks = 0; ks < 2; ++ks)
          af[mh][m][ks] = *(const bf16x8*)(base + ra * 64 + (((ks * 4 + lq) ^ (ra & 7)) * 8));
      }
    }
  };
  auto LOAD_B = [&](int buf, int nh) {
    const bf16* base = S + (((buf << 2) | 2 | nh) << 13);
#pragma unroll
    for (int n = 0; n < 4; ++n) {
      int rb = wcol * 64 + n * 16 + lr;
#pragma unroll
      for (int ks = 0; ks < 2; ++ks)
        bfr[n][ks] = *(const bf16x8*)(base + rb * 64 + (((ks * 4 + lq) ^ (rb & 7)) * 8));
    }
  };
  auto MFMA_Q = [&](int qd, int mh) {
#pragma unroll
    for (int m = 0; m < 2; ++m)
#pragma unroll
      for (int n = 0; n < 4; ++n)
#pragma unroll
        for (int ks = 0; ks < 2; ++ks)
          acc[qd][m][n] = __builtin_amdgcn_mfma_f32_16x16x32_bf16(
              af[mh][m][ks], bfr[n][ks], acc[qd][m][n], 0, 0, 0);
  };

  STAGE(0, 0, 0); STAGE(0, 1, 0); STAGE(1, 0, 0); STAGE(1, 1, 0);
  STAGE(0, 0, 1); STAGE(0, 1, 1); STAGE(1, 0, 1);
  asm volatile("s_waitcnt vmcnt(6)" ::: "memory");
  __builtin_amdgcn_sched_barrier(0);
  __builtin_amdgcn_s_barrier();

  for (int t = 0; t < NT; ++t) {
    const int buf = t & 1;
    LOAD_A(buf);
    LOAD_B(buf, 0);
    STAGE(1, 1, t + 1);
    __builtin_amdgcn_s_barrier();
    asm volatile("s_waitcnt lgkmcnt(0)" ::: "memory");
    __builtin_amdgcn_sched_barrier(0);
    __builtin_amdgcn_s_setprio(1);
    MFMA_Q(0, 0);
    __builtin_amdgcn_s_setprio(0);
    __builtin_amdgcn_sched_barrier(0);
    __builtin_amdgcn_s_barrier();
    STAGE(0, 0, t + 2);
    __builtin_amdgcn_s_barrier();
    __builtin_amdgcn_s_setprio(1);
    MFMA_Q(1, 1);
    __builtin_amdgcn_s_setprio(0);
    __builtin_amdgcn_sched_barrier(0);
    __builtin_amdgcn_s_barrier();
    LOAD_B(buf, 1);
    STAGE(0, 1, t + 2);
    __builtin_amdgcn_s_barrier();
    asm volatile("s_waitcnt lgkmcnt(0)" ::: "memory");
    __builtin_amdgcn_sched_barrier(0);
    __builtin_amdgcn_s_setprio(1);
    MFMA_Q(2, 1);
    __builtin_amdgcn_s_setprio(0);
    __builtin_amdgcn_sched_barrier(0);
    __builtin_amdgcn_s_barrier();
    STAGE(1, 0, t + 2);
    asm volatile("s_waitcnt vmcnt(6)" ::: "memory");
    __builtin_amdgcn_sched_barrier(0);
    __builtin_amdgcn_s_barrier();
    __builtin_amdgcn_s_setprio(1);
    MFMA_Q(3, 0);
    __builtin_amdgcn_s_setprio(0);
    __builtin_amdgcn_sched_barrier(0);
    __builtin_amdgcn_s_barrier();
  }

#pragma unroll
  for (int qd = 0; qd < 4; ++qd) {
    const int mh = (qd == 1 || qd == 2) ? 1 : 0;
    const int nh = (qd >= 2) ? 1 : 0;
#pragma unroll
    for (int m = 0; m < 2; ++m)
#pragma unroll
      for (int n = 0; n < 4; ++n)
#pragma unroll
        for (int j = 0; j < 4; ++j) {
          int row = by * 256 + mh * 128 + wrow * 32 + m * 16 + lq * 4 + j;
          int col = bx * 256 + nh * 128 + wcol * 64 + n * 16 + lr;
          if (OUT_F32) ((float*)Cout)[(size_t)row * N + col] = acc[qd][m][n][j];
          else         ((bf16*)Cout)[(size_t)row * N + col] = (bf16)acc[qd][m][n][j];
        }
  }
}

// ---------------- fused RMSNorm + RoPE + split ----------------
__global__ __launch_bounds__(256) void norm_rope_k(const bf16* __restrict__ qkv,
                                                   const float* __restrict__ qn_w,
                                                   const float* __restrict__ kn_w,
                                                   const float* __restrict__ sinb,
                                                   const float* __restrict__ cosb,
                                                   bf16* __restrict__ qro,
                                                   bf16* __restrict__ kro,
                                                   bf16* __restrict__ vo) {
  const int bt = blockIdx.x;
  const int tid = threadIdx.x, lane = tid & 63, wid = tid >> 6;
  const bf16* row = qkv + (size_t)bt * NQKV;
  const float sv = sinb[bt * 64 + lane];
  const float cv = cosb[bt * 64 + lane];
  for (int it = 0; it < 8; ++it) {
    int hv = it * 4 + wid;   // 0..31 : 0-15 q, 16-23 k, 24-31 v
    int off = (hv < 16) ? hv * 128 : (hv < 24) ? 2048 + (hv - 16) * 128 : 3072 + (hv - 24) * 128;
    float e0 = (float)row[off + lane];
    float e1 = (float)row[off + 64 + lane];
    if (hv >= 24) {
      bf16* dst = vo + (size_t)bt * (KVH * HDIM) + (hv - 24) * 128;
      dst[lane] = (bf16)e0;
      dst[64 + lane] = (bf16)e1;
    } else {
      float ss = e0 * e0 + e1 * e1;
#pragma unroll
      for (int o = 32; o >= 1; o >>= 1) ss += __shfl_xor(ss, o, 64);
      float rms = rsqrtf(ss * (1.0f / 128.0f) + RMS_EPS);
      const float* wn = (hv < 16) ? qn_w : kn_w;
      float n0 = e0 * rms * wn[lane];
      float n1 = e1 * rms * wn[lane + 64];
      float o0 = n0 * cv - n1 * sv;
      float o1 = n1 * cv + n0 * sv;
      if (hv < 16) {
        bf16* dst = qro + (size_t)bt * (HH * HDIM) + hv * 128;
        dst[lane] = (bf16)o0; dst[64 + lane] = (bf16)o1;
      } else {
        bf16* dst = kro + (size_t)bt * (KVH * HDIM) + (hv - 16) * 128;
        dst[lane] = (bf16)o0; dst[64 + lane] = (bf16)o1;
      }
    }
  }
}

// ---------------- GQA causal flash attention, v3 ----------------
// grid (TQ, H, B); 8 waves (512 thr), QBLK=128 (16 q-rows/wave), KVBLK=64.
// K/V TRIPLE-buffered in LDS, prefetch distance 2, counted per-wave
// s_waitcnt vmcnt(4) + ONE raw s_barrier per tile (loads span barriers; the
// barrier never drains vmcnt). Defer-max (T13): skip O-rescale while
// pm <= mrun+8. No setprio (measured regression in lockstep structure).
__global__ __launch_bounds__(512, 2)
void attn3_k(const bf16* __restrict__ qr, const bf16* __restrict__ kr,
             const bf16* __restrict__ vbt, bf16* __restrict__ ao) {
  __shared__ bf16 Ks[3][64 * 128];
  __shared__ bf16 Vs[3][128 * 64];
  __shared__ bf16 Ps[8 * 16 * 64];
  const int tid = threadIdx.x, lane = tid & 63, wid = tid >> 6;
  const int lr = lane & 15, lq = lane >> 4;
  const int h = blockIdx.y, b = blockIdx.z;
  const int qt = (b & 1) ? (TQ - 1 - blockIdx.x) : blockIdx.x;
  const int kvh = h >> 1;            // N_REP = 2
  const int q0 = qt * 128 + wid * 16;
  const int nt = 2 * qt + 2;

  const int krow0 = lane >> 4, kcc = lane & 15;   // K: row = chunk*4 + krow0
  const int vrow0 = lane >> 3, vcc = lane & 7;    // V: row = chunk*8 + vrow0

  // one STAGE = exactly 4 gl_lds16 per wave (vmcnt accounting relies on this)
  auto STAGE = [&](int bufi, int kt) {
    int ktc = kt < nt ? kt : nt - 1;   // clamp: keep load count uniform
#pragma unroll
    for (int i = 0; i < 2; ++i) {
      int chunk = i * 8 + wid;
      int krow = chunk * 4 + krow0;
      gl_lds16(&kr[(((size_t)(b * TT + ktc * 64 + krow)) * KVH + kvh) * HDIM + ((kcc ^ (krow & 7)) * 8)],
               &Ks[bufi][chunk * 512]);
      int drow = chunk * 8 + vrow0;
      gl_lds16(&vbt[(((size_t)(b * KVH + kvh)) * HDIM + drow) * TT + ktc * 64 + ((vcc ^ (drow & 7)) * 8)],
               &Vs[bufi][chunk * 512]);
    }
  };

  bf16x8 aq[4];
#pragma unroll
  for (int kk = 0; kk < 4; ++kk)
    aq[kk] = *(const bf16x8*)&qr[(((size_t)(b * TT + q0 + lr)) * HH + h) * HDIM + kk * 32 + lq * 8];

  f32x4 accO[8] = {};
  float mrun[4], lrun[4];
#pragma unroll
  for (int r = 0; r < 4; ++r) { mrun[r] = -INFINITY; lrun[r] = 0.f; }

  // prologue: stage tiles 0,1; wait own tile-0 loads; rendezvous
  STAGE(0, 0);
  STAGE(1, 1);
  asm volatile("s_waitcnt vmcnt(4)" ::: "memory");
  __builtin_amdgcn_sched_barrier(0);
  __builtin_amdgcn_s_barrier();
  __builtin_amdgcn_sched_barrier(0);

  int buf = 0;
  for (int kt = 0; kt < nt; ++kt) {
    const int sb = (buf + 2 >= 3) ? buf - 1 : buf + 2;
    STAGE(sb, kt + 2);

    if (kt * 64 <= q0 + 15) {   // wave-uniform: skip fully-masked tiles
      const bf16* Kb = &Ks[buf][0];
      const bf16* Vb = &Vs[buf][0];
      // ---- S = Q K^T ----
      f32x4 sacc[4];
#pragma unroll
      for (int ct = 0; ct < 4; ++ct) {
        sacc[ct] = (f32x4){0.f, 0.f, 0.f, 0.f};
        int krow = ct * 16 + lr;
#pragma unroll
        for (int kk = 0; kk < 4; ++kk) {
          bf16x8 bk = *(const bf16x8*)((const char*)Kb + krow * 256 + (((kk * 4 + lq) ^ (krow & 7)) * 16));
          sacc[ct] = __builtin_amdgcn_mfma_f32_16x16x32_bf16(aq[kk], bk, sacc[ct], 0, 0, 0);
        }
      }

      // ---- mask, scale, online softmax with defer-max ----
      const bool domask = (kt * 64 + 63 > q0);
      float p[4][4];
      float pm[4] = {-INFINITY, -INFINITY, -INFINITY, -INFINITY};
#pragma unroll
      for (int ct = 0; ct < 4; ++ct) {
        int col = kt * 64 + ct * 16 + lr;
#pragma unroll
        for (int r = 0; r < 4; ++r) {
          int rowg = q0 + lq * 4 + r;
          float s = (!domask || col <= rowg) ? sacc[ct][r] * ATT_SCALE : -INFINITY;
          p[ct][r] = s;
          pm[r] = fmaxf(pm[r], s);
        }
      }
#pragma unroll
      for (int r = 0; r < 4; ++r) {
#pragma unroll
        for (int o = 1; o < 16; o <<= 1) pm[r] = fmaxf(pm[r], __shfl_xor(pm[r], o, 64));
      }
      // defer-max: only rescale when some row max grew past mrun+8
      int needup = (pm[0] > mrun[0] + 8.f) || (pm[1] > mrun[1] + 8.f) ||
                   (pm[2] > mrun[2] + 8.f) || (pm[3] > mrun[3] + 8.f);
      if (__any(needup)) {
        float alpha[4];
#pragma unroll
        for (int r = 0; r < 4; ++r) {
          float mnew = fmaxf(mrun[r], pm[r]);
          alpha[r] = __expf(mrun[r] - mnew);
          mrun[r] = mnew;
          lrun[r] *= alpha[r];
        }
#pragma unroll
        for (int n = 0; n < 8; ++n)
#pragma unroll
          for (int r = 0; r < 4; ++r) accO[n][r] *= alpha[r];
      }
      float rs[4] = {0.f, 0.f, 0.f, 0.f};
#pragma unroll
      for (int ct = 0; ct < 4; ++ct)
#pragma unroll
        for (int r = 0; r < 4; ++r) {
          float e = __expf(p[ct][r] - mrun[r]);
          p[ct][r] = e;
          rs[r] += e;
        }
#pragma unroll
      for (int r = 0; r < 4; ++r) {
#pragma unroll
        for (int o = 1; o < 16; o <<= 1) rs[r] += __shfl_xor(rs[r], o, 64);
        lrun[r] += rs[r];
      }

      // ---- write P to per-wave swizzled LDS ----
#pragma unroll
      for (int ct = 0; ct < 4; ++ct)
#pragma unroll
        for (int r = 0; r < 4; ++r) {
          int prow = lq * 4 + r;
          int col = ct * 16 + lr;
          int cc = col >> 3;
          char* pb = (char*)Ps + (wid * 16 + prow) * 128 + ((cc ^ (prow & 7)) * 16) + (col & 7) * 2;
          *(bf16*)pb = (bf16)p[ct][r];
        }

      // ---- O += P V ----
#pragma unroll
      for (int c = 0; c < 2; ++c) {
        bf16x8 ap = *(const bf16x8*)((const char*)Ps + (wid * 16 + lr) * 128 + (((c * 4 + lq) ^ (lr & 7)) * 16));
#pragma unroll
        for (int n = 0; n < 8; ++n) {
          int drow = n * 16 + lr;
          bf16x8 bv = *(const bf16x8*)((const char*)Vb + drow * 128 + (((c * 4 + lq) ^ (drow & 7)) * 16));
          accO[n] = __builtin_amdgcn_mfma_f32_16x16x32_bf16(ap, bv, accO[n], 0, 0, 0);
        }
      }
    }

    // counted wait: own tile-(kt+1) loads landed; leaves tile-(kt+2) in flight
    asm volatile("s_waitcnt vmcnt(4)" ::: "memory");
    __builtin_amdgcn_sched_barrier(0);
    __builtin_amdgcn_s_barrier();
    __builtin_amdgcn_sched_barrier(0);
    buf = (buf == 2) ? 0 : buf + 1;
  }

  float inv[4];
#pragma unroll
  for (int r = 0; r < 4; ++r) inv[r] = 1.0f / lrun[r];
#pragma unroll
  for (int n = 0; n < 8; ++n)
#pragma unroll
    for (int r = 0; r < 4; ++r) {
      size_t idx = (((size_t)(b * TT + q0 + lq * 4 + r)) * HH + h) * HDIM + n * 16 + lr;
      ao[idx] = (bf16)(accO[n][r] * inv[r]);
    }
}

// ---------------- launcher ----------------
extern "C" void kernel_launch(void* const* d_in, const int* in_sizes, int n_in,
                              void* d_out, int out_size, void* d_ws, size_t ws_size,
                              hipStream_t stream) {
  const float* x    = (const float*)d_in[0];
  const float* wq   = (const float*)d_in[1];
  const float* wk   = (const float*)d_in[2];
  const float* wv   = (const float*)d_in[3];
  const float* wo   = (const float*)d_in[4];
  const float* qn_w = (const float*)d_in[5];
  const float* kn_w = (const float*)d_in[6];
  const float* sinb = (const float*)d_in[7];
  const float* cosb = (const float*)d_in[8];
  float* out = (float*)d_out;

  char* ws = (char*)d_ws;
  size_t off = 0;
  auto alloc = [&](size_t bytes) {
    char* p = ws + off;
    off += (bytes + 255) & ~(size_t)255;
    return p;
  };
  bf16* xb  = (bf16*)alloc((size_t)BT * DD * 2);       // x bf16 (reused as attn out)
  bf16* Wt  = (bf16*)alloc((size_t)NQKV * DD * 2);     // [wq|wk|wv]^T (reused as q_rope)
  bf16* Wot = (bf16*)alloc((size_t)DD * DD * 2);       // wo^T
  bf16* qkv = (bf16*)alloc((size_t)BT * NQKV * 2);     // fused qkv
  bf16* kro = (bf16*)alloc((size_t)BT * KVH * HDIM * 2);
  bf16* vb  = (bf16*)alloc((size_t)BT * KVH * HDIM * 2);
  bf16* vbt = (bf16*)alloc((size_t)BT * KVH * HDIM * 2);
  bf16* qro = Wt;   // alias: Wt dead after QKV GEMM
  bf16* aob = xb;   // alias: xb dead after QKV GEMM
  (void)ws_size; (void)in_sizes; (void)n_in; (void)out_size;

  cast_bf16_k<<<2048, 256, 0, stream>>>(x, xb, BT * DD / 4);
  transpose_cast_k<<<dim3(2048 / 32, 2048 / 32), 256, 0, stream>>>(wq, Wt, 2048, 2048);
  transpose_cast_k<<<dim3(1024 / 32, 2048 / 32), 256, 0, stream>>>(wk, Wt + (size_t)2048 * 2048, 2048, 1024);
  transpose_cast_k<<<dim3(1024 / 32, 2048 / 32), 256, 0, stream>>>(wv, Wt + (size_t)3072 * 2048, 2048, 1024);
  transpose_cast_k<<<dim3(2048 / 32, 2048 / 32), 256, 0, stream>>>(wo, Wot, 2048, 2048);

  // QKV GEMM: 256^2 8-phase (M=4096, N=4096 -> 256 blocks, 1/CU)
  gemm256_k<0><<<dim3((BT / 256) * (NQKV / 256)), 512, 0, stream>>>(xb, Wt, qkv, BT, NQKV, DD);

  norm_rope_k<<<BT, 256, 0, stream>>>(qkv, qn_w, kn_w, sinb, cosb, qro, kro, vb);
  transpose_v_k<<<dim3(TT / 32, HDIM / 32, BB * KVH), 256, 0, stream>>>(vb, vbt);

  attn3_k<<<dim3(TQ, HH, BB), 512, 0, stream>>>(qro, kro, vbt, aob);

  gemm_bt_k<1><<<dim3(DD / 128, BT / 128), 256, 0, stream>>>(aob, Wot, out, BT, DD, DD);
}

// Round 5
// 243.963 us; speedup vs baseline: 1.1287x; 1.1287x over previous
//
#include <hip/hip_runtime.h>
#include <hip/hip_bf16.h>
#include <stdint.h>

// ---------------- problem constants ----------------
#define BB 2
#define TT 2048
#define DD 2048
#define HH 16
#define KVH 8
#define HDIM 128
#define BT (BB*TT)            // 4096
#define NQKV (HH*HDIM + 2*KVH*HDIM) // 4096
#define TQ (TT/128)           // 16 q-blocks of 128 rows
#define ATT_SCALE 0.08838834764831845f
#define RMS_EPS 1e-6f

typedef __bf16 bf16;
typedef __bf16 bf16x8 __attribute__((ext_vector_type(8)));
typedef __bf16 bf16x4 __attribute__((ext_vector_type(4)));
typedef float  f32x4  __attribute__((ext_vector_type(4)));

// async global->LDS, 16B per lane. LDS dest = wave-uniform base + lane*16.
__device__ __forceinline__ void gl_lds16(const void* g, const void* l) {
  __builtin_amdgcn_global_load_lds(
      (const __attribute__((address_space(1))) void*)(uintptr_t)g,
      (__attribute__((address_space(3))) void*)(uint32_t)(uintptr_t)l,
      16, 0, 0);
}

// ---------------- elementwise f32 -> bf16 cast ----------------
__global__ __launch_bounds__(256) void cast_bf16_k(const float* __restrict__ in,
                                                   bf16* __restrict__ out, int n4) {
  int i = blockIdx.x * blockDim.x + threadIdx.x;
  int stride = gridDim.x * blockDim.x;
  for (; i < n4; i += stride) {
    float4 v = ((const float4*)in)[i];
    bf16x4 o = { (bf16)v.x, (bf16)v.y, (bf16)v.z, (bf16)v.w };
    *(bf16x4*)(out + (size_t)i * 4) = o;
  }
}

// ---------------- f32 (R x C) -> bf16 (C x R) transpose-cast ----------------
__global__ __launch_bounds__(256) void transpose_cast_k(const float* __restrict__ in,
                                                        bf16* __restrict__ out,
                                                        int R, int C) {
  __shared__ float tile[32][33];
  int tx = threadIdx.x & 31, ty = threadIdx.x >> 5;
  int c0 = blockIdx.x * 32, r0 = blockIdx.y * 32;
#pragma unroll
  for (int i = 0; i < 4; ++i)
    tile[ty + 8*i][tx] = in[(size_t)(r0 + ty + 8*i) * C + c0 + tx];
  __syncthreads();
#pragma unroll
  for (int i = 0; i < 4; ++i)
    out[(size_t)(c0 + ty + 8*i) * R + r0 + tx] = (bf16)tile[tx][ty + 8*i];
}

// ---------------- bf16 V transpose: (B,T,KV,HD) -> (B,KV,HD,T) ----------------
__global__ __launch_bounds__(256) void transpose_v_k(const bf16* __restrict__ vb,
                                                     bf16* __restrict__ vbt) {
  __shared__ bf16 tile[32][33];
  int tx = threadIdx.x & 31, ty = threadIdx.x >> 5;
  int t0 = blockIdx.x * 32;
  int d0 = blockIdx.y * 32;
  int bk = blockIdx.z;                 // b*KV + kv
  int b = bk >> 3, kv = bk & 7;
#pragma unroll
  for (int i = 0; i < 4; ++i)
    tile[ty + 8*i][tx] = vb[(((size_t)(b*TT + t0 + ty + 8*i)) * KVH + kv) * HDIM + d0 + tx];
  __syncthreads();
#pragma unroll
  for (int i = 0; i < 4; ++i)
    vbt[(((size_t)bk) * HDIM + d0 + ty + 8*i) * TT + t0 + tx] = tile[tx][ty + 8*i];
}

// ---------------- GEMM 256x256, BK=64, 8-phase counted-vmcnt schedule ----------------
template <int OUT_F32>
__global__ __launch_bounds__(512, 2)
void gemm256_k(const bf16* __restrict__ A, const bf16* __restrict__ Bt,
               void* __restrict__ Cout, int M, int N, int K) {
  __shared__ bf16 S[2 * 2 * 2 * 128 * 64];   // 128 KiB
  const int tid = threadIdx.x, lane = tid & 63, wid = tid >> 6;
  const int lr = lane & 15, lq = lane >> 4;
  const int wrow = wid >> 1, wcol = wid & 1;

  // XCD-aware bijective swizzle of the flat block id (nwg % 8 == 0 here)
  const int nwg = gridDim.x;
  const int o = blockIdx.x;
  const int ns = (o & 7) * (nwg >> 3) + (o >> 3);
  const int GX = N >> 8;
  const int by = ns / GX, bx = ns % GX;

  const int NT = K >> 6;
  const bf16* Ab = A + (size_t)(by * 256) * K;
  const bf16* Bb = Bt + (size_t)(bx * 256) * K;

  const int srow = tid >> 3;
  const size_t soff = (size_t)srow * K + (((tid & 7) ^ (srow & 7)) * 8);
  const int ldst0 = wid * 512;

  auto STAGE = [&](int op, int h, int t_) {
    int tc = t_ < NT ? t_ : NT - 1;
    const bf16* src = (op ? Bb : Ab) + soff + (size_t)(h * 128) * K + tc * 64;
    bf16* dst = S + ((((((t_ & 1) << 1) | op) << 1) | h) << 13) + ldst0;
#pragma unroll
    for (int i = 0; i < 2; ++i)
      gl_lds16(src + (size_t)(i * 64) * K, dst + i * 4096);
  };

  bf16x8 af[2][2][2];   // [mh][m][ks]
  bf16x8 bfr[4][2];     // [n][ks]
  f32x4 acc[4][2][4] = {};  // [quad][m][n]

  auto LOAD_A = [&](int buf) {
#pragma unroll
    for (int mh = 0; mh < 2; ++mh) {
      const bf16* base = S + (((buf << 2) | mh) << 13);
#pragma unroll
      for (int m = 0; m < 2; ++m) {
        int ra = wrow * 32 + m * 16 + lr;
#pragma unroll
        for (int ks = 0; ks < 2; ++ks)
          af[mh][m][ks] = *(const bf16x8*)(base + ra * 64 + (((ks * 4 + lq) ^ (ra & 7)) * 8));
      }
    }
  };
  auto LOAD_B = [&](int buf, int nh) {
    const bf16* base = S + (((buf << 2) | 2 | nh) << 13);
#pragma unroll
    for (int n = 0; n < 4; ++n) {
      int rb = wcol * 64 + n * 16 + lr;
#pragma unroll
      for (int ks = 0; ks < 2; ++ks)
        bfr[n][ks] = *(const bf16x8*)(base + rb * 64 + (((ks * 4 + lq) ^ (rb & 7)) * 8));
    }
  };
  auto MFMA_Q = [&](int qd, int mh) {
#pragma unroll
    for (int m = 0; m < 2; ++m)
#pragma unroll
      for (int n = 0; n < 4; ++n)
#pragma unroll
        for (int ks = 0; ks < 2; ++ks)
          acc[qd][m][n] = __builtin_amdgcn_mfma_f32_16x16x32_bf16(
              af[mh][m][ks], bfr[n][ks], acc[qd][m][n], 0, 0, 0);
  };

  STAGE(0, 0, 0); STAGE(0, 1, 0); STAGE(1, 0, 0); STAGE(1, 1, 0);
  STAGE(0, 0, 1); STAGE(0, 1, 1); STAGE(1, 0, 1);
  asm volatile("s_waitcnt vmcnt(6)" ::: "memory");
  __builtin_amdgcn_sched_barrier(0);
  __builtin_amdgcn_s_barrier();

  for (int t = 0; t < NT; ++t) {
    const int buf = t & 1;
    LOAD_A(buf);
    LOAD_B(buf, 0);
    STAGE(1, 1, t + 1);
    __builtin_amdgcn_s_barrier();
    asm volatile("s_waitcnt lgkmcnt(0)" ::: "memory");
    __builtin_amdgcn_sched_barrier(0);
    __builtin_amdgcn_s_setprio(1);
    MFMA_Q(0, 0);
    __builtin_amdgcn_s_setprio(0);
    __builtin_amdgcn_sched_barrier(0);
    __builtin_amdgcn_s_barrier();
    STAGE(0, 0, t + 2);
    __builtin_amdgcn_s_barrier();
    __builtin_amdgcn_s_setprio(1);
    MFMA_Q(1, 1);
    __builtin_amdgcn_s_setprio(0);
    __builtin_amdgcn_sched_barrier(0);
    __builtin_amdgcn_s_barrier();
    LOAD_B(buf, 1);
    STAGE(0, 1, t + 2);
    __builtin_amdgcn_s_barrier();
    asm volatile("s_waitcnt lgkmcnt(0)" ::: "memory");
    __builtin_amdgcn_sched_barrier(0);
    __builtin_amdgcn_s_setprio(1);
    MFMA_Q(2, 1);
    __builtin_amdgcn_s_setprio(0);
    __builtin_amdgcn_sched_barrier(0);
    __builtin_amdgcn_s_barrier();
    STAGE(1, 0, t + 2);
    asm volatile("s_waitcnt vmcnt(6)" ::: "memory");
    __builtin_amdgcn_sched_barrier(0);
    __builtin_amdgcn_s_barrier();
    __builtin_amdgcn_s_setprio(1);
    MFMA_Q(3, 0);
    __builtin_amdgcn_s_setprio(0);
    __builtin_amdgcn_sched_barrier(0);
    __builtin_amdgcn_s_barrier();
  }

#pragma unroll
  for (int qd = 0; qd < 4; ++qd) {
    const int mh = (qd == 1 || qd == 2) ? 1 : 0;
    const int nh = (qd >= 2) ? 1 : 0;
#pragma unroll
    for (int m = 0; m < 2; ++m)
#pragma unroll
      for (int n = 0; n < 4; ++n)
#pragma unroll
        for (int j = 0; j < 4; ++j) {
          int row = by * 256 + mh * 128 + wrow * 32 + m * 16 + lq * 4 + j;
          int col = bx * 256 + nh * 128 + wcol * 64 + n * 16 + lr;
          if (OUT_F32) ((float*)Cout)[(size_t)row * N + col] = acc[qd][m][n][j];
          else         ((bf16*)Cout)[(size_t)row * N + col] = (bf16)acc[qd][m][n][j];
        }
  }
}

// ---------------- fused RMSNorm + RoPE + split ----------------
__global__ __launch_bounds__(256) void norm_rope_k(const bf16* __restrict__ qkv,
                                                   const float* __restrict__ qn_w,
                                                   const float* __restrict__ kn_w,
                                                   const float* __restrict__ sinb,
                                                   const float* __restrict__ cosb,
                                                   bf16* __restrict__ qro,
                                                   bf16* __restrict__ kro,
                                                   bf16* __restrict__ vo) {
  const int bt = blockIdx.x;
  const int tid = threadIdx.x, lane = tid & 63, wid = tid >> 6;
  const bf16* row = qkv + (size_t)bt * NQKV;
  const float sv = sinb[bt * 64 + lane];
  const float cv = cosb[bt * 64 + lane];
  for (int it = 0; it < 8; ++it) {
    int hv = it * 4 + wid;   // 0..31 : 0-15 q, 16-23 k, 24-31 v
    int off = (hv < 16) ? hv * 128 : (hv < 24) ? 2048 + (hv - 16) * 128 : 3072 + (hv - 24) * 128;
    float e0 = (float)row[off + lane];
    float e1 = (float)row[off + 64 + lane];
    if (hv >= 24) {
      bf16* dst = vo + (size_t)bt * (KVH * HDIM) + (hv - 24) * 128;
      dst[lane] = (bf16)e0;
      dst[64 + lane] = (bf16)e1;
    } else {
      float ss = e0 * e0 + e1 * e1;
#pragma unroll
      for (int o = 32; o >= 1; o >>= 1) ss += __shfl_xor(ss, o, 64);
      float rms = rsqrtf(ss * (1.0f / 128.0f) + RMS_EPS);
      const float* wn = (hv < 16) ? qn_w : kn_w;
      float n0 = e0 * rms * wn[lane];
      float n1 = e1 * rms * wn[lane + 64];
      float o0 = n0 * cv - n1 * sv;
      float o1 = n1 * cv + n0 * sv;
      if (hv < 16) {
        bf16* dst = qro + (size_t)bt * (HH * HDIM) + hv * 128;
        dst[lane] = (bf16)o0; dst[64 + lane] = (bf16)o1;
      } else {
        bf16* dst = kro + (size_t)bt * (KVH * HDIM) + (hv - 16) * 128;
        dst[lane] = (bf16)o0; dst[64 + lane] = (bf16)o1;
      }
    }
  }
}

// ---------------- GQA causal flash attention, v4 ----------------
// R2 structure (proven fastest): 8 waves, QBLK=128, KVBLK=64, K/V double-
// buffered, STAGE(next)->compute(cur)->__syncthreads per tile, no setprio.
// New: (a) defer-max (T13) — skip O-rescale while tile max <= mrun+8;
// (b) ones-column PV — row-sum l accumulated by 2 extra MFMA into acc1
//     (rescaled with O), removing the 16-shfl sum-reduce per tile.
__global__ __launch_bounds__(512, 4)
void attn4_k(const bf16* __restrict__ qr, const bf16* __restrict__ kr,
             const bf16* __restrict__ vbt, bf16* __restrict__ ao) {
  __shared__ bf16 Ks[2][64 * 128];
  __shared__ bf16 Vs[2][128 * 64];
  __shared__ bf16 Ps[8 * 16 * 64];
  const int tid = threadIdx.x, lane = tid & 63, wid = tid >> 6;
  const int lr = lane & 15, lq = lane >> 4;
  const int h = blockIdx.y, b = blockIdx.z;
  const int qt = (b & 1) ? (TQ - 1 - blockIdx.x) : blockIdx.x;
  const int kvh = h >> 1;            // N_REP = 2
  const int q0 = qt * 128 + wid * 16;
  const int nt = 2 * qt + 2;

  const int krow0 = lane >> 4, kcc = lane & 15;   // K: row = chunk*4 + krow0
  const int vrow0 = lane >> 3, vcc = lane & 7;    // V: row = chunk*8 + vrow0

  auto STAGE = [&](int bufi, int kt) {
#pragma unroll
    for (int i = 0; i < 2; ++i) {
      int chunk = i * 8 + wid;
      int krow = chunk * 4 + krow0;
      gl_lds16(&kr[(((size_t)(b * TT + kt * 64 + krow)) * KVH + kvh) * HDIM + ((kcc ^ (krow & 7)) * 8)],
               &Ks[bufi][chunk * 512]);
      int drow = chunk * 8 + vrow0;
      gl_lds16(&vbt[(((size_t)(b * KVH + kvh)) * HDIM + drow) * TT + kt * 64 + ((vcc ^ (drow & 7)) * 8)],
               &Vs[bufi][chunk * 512]);
    }
  };

  bf16x8 aq[4];
#pragma unroll
  for (int kk = 0; kk < 4; ++kk)
    aq[kk] = *(const bf16x8*)&qr[(((size_t)(b * TT + q0 + lr)) * HH + h) * HDIM + kk * 32 + lq * 8];

  bf16x8 vones;
#pragma unroll
  for (int j = 0; j < 8; ++j) vones[j] = (bf16)1.0f;

  f32x4 accO[8] = {};
  f32x4 acc1 = {};          // row-sum accumulator (all 16 cols identical)
  float mrun[4];
#pragma unroll
  for (int r = 0; r < 4; ++r) mrun[r] = -INFINITY;

  int buf = 0;
  STAGE(0, 0);
  __syncthreads();

  for (int kt = 0; kt < nt; ++kt) {
    if (kt + 1 < nt) STAGE(buf ^ 1, kt + 1);

    if (kt * 64 <= q0 + 15) {   // wave-uniform: skip fully-masked tiles
      // ---- S = Q K^T ----
      f32x4 sacc[4];
#pragma unroll
      for (int ct = 0; ct < 4; ++ct) {
        sacc[ct] = (f32x4){0.f, 0.f, 0.f, 0.f};
        int krow = ct * 16 + lr;
#pragma unroll
        for (int kk = 0; kk < 4; ++kk) {
          bf16x8 bk = *(const bf16x8*)((const char*)&Ks[buf][0] + krow * 256 + (((kk * 4 + lq) ^ (krow & 7)) * 16));
          sacc[ct] = __builtin_amdgcn_mfma_f32_16x16x32_bf16(aq[kk], bk, sacc[ct], 0, 0, 0);
        }
      }

      // ---- mask, scale, tile max ----
      const bool domask = (kt * 64 + 63 > q0);
      float p[4][4];
      float pm[4] = {-INFINITY, -INFINITY, -INFINITY, -INFINITY};
#pragma unroll
      for (int ct = 0; ct < 4; ++ct) {
        int col = kt * 64 + ct * 16 + lr;
#pragma unroll
        for (int r = 0; r < 4; ++r) {
          int rowg = q0 + lq * 4 + r;
          float s = (!domask || col <= rowg) ? sacc[ct][r] * ATT_SCALE : -INFINITY;
          p[ct][r] = s;
          pm[r] = fmaxf(pm[r], s);
        }
      }
#pragma unroll
      for (int r = 0; r < 4; ++r) {
#pragma unroll
        for (int o = 1; o < 16; o <<= 1) pm[r] = fmaxf(pm[r], __shfl_xor(pm[r], o, 64));
      }

      // ---- defer-max (T13): rescale only when max grew past mrun+8 ----
      int needup = (pm[0] > mrun[0] + 8.f) || (pm[1] > mrun[1] + 8.f) ||
                   (pm[2] > mrun[2] + 8.f) || (pm[3] > mrun[3] + 8.f);
      if (__any(needup)) {
        float alpha[4];
#pragma unroll
        for (int r = 0; r < 4; ++r) {
          float mnew = fmaxf(mrun[r], pm[r]);
          alpha[r] = __expf(mrun[r] - mnew);
          mrun[r] = mnew;
        }
#pragma unroll
        for (int n = 0; n < 8; ++n)
#pragma unroll
          for (int r = 0; r < 4; ++r) accO[n][r] *= alpha[r];
#pragma unroll
        for (int r = 0; r < 4; ++r) acc1[r] *= alpha[r];
      }

      // ---- P = exp(S - mrun); write to per-wave swizzled LDS ----
#pragma unroll
      for (int ct = 0; ct < 4; ++ct)
#pragma unroll
        for (int r = 0; r < 4; ++r) {
          float e = __expf(p[ct][r] - mrun[r]);
          int prow = lq * 4 + r;
          int col = ct * 16 + lr;
          int cc = col >> 3;
          char* pb = (char*)Ps + (wid * 16 + prow) * 128 + ((cc ^ (prow & 7)) * 16) + (col & 7) * 2;
          *(bf16*)pb = (bf16)e;
        }

      // ---- O += P V ; l += P @ ones ----
#pragma unroll
      for (int c = 0; c < 2; ++c) {
        bf16x8 ap = *(const bf16x8*)((const char*)Ps + (wid * 16 + lr) * 128 + (((c * 4 + lq) ^ (lr & 7)) * 16));
        acc1 = __builtin_amdgcn_mfma_f32_16x16x32_bf16(ap, vones, acc1, 0, 0, 0);
#pragma unroll
        for (int n = 0; n < 8; ++n) {
          int drow = n * 16 + lr;
          bf16x8 bv = *(const bf16x8*)((const char*)&Vs[buf][0] + drow * 128 + (((c * 4 + lq) ^ (drow & 7)) * 16));
          accO[n] = __builtin_amdgcn_mfma_f32_16x16x32_bf16(ap, bv, accO[n], 0, 0, 0);
        }
      }
    }

    __syncthreads();   // drains vmcnt: next tile staged & this tile's reads done
    buf ^= 1;
  }

  float inv[4];
#pragma unroll
  for (int r = 0; r < 4; ++r) inv[r] = 1.0f / acc1[r];
#pragma unroll
  for (int n = 0; n < 8; ++n)
#pragma unroll
    for (int r = 0; r < 4; ++r) {
      size_t idx = (((size_t)(b * TT + q0 + lq * 4 + r)) * HH + h) * HDIM + n * 16 + lr;
      ao[idx] = (bf16)(accO[n][r] * inv[r]);
    }
}

// ---------------- launcher ----------------
extern "C" void kernel_launch(void* const* d_in, const int* in_sizes, int n_in,
                              void* d_out, int out_size, void* d_ws, size_t ws_size,
                              hipStream_t stream) {
  const float* x    = (const float*)d_in[0];
  const float* wq   = (const float*)d_in[1];
  const float* wk   = (const float*)d_in[2];
  const float* wv   = (const float*)d_in[3];
  const float* wo   = (const float*)d_in[4];
  const float* qn_w = (const float*)d_in[5];
  const float* kn_w = (const float*)d_in[6];
  const float* sinb = (const float*)d_in[7];
  const float* cosb = (const float*)d_in[8];
  float* out = (float*)d_out;

  char* ws = (char*)d_ws;
  size_t off = 0;
  auto alloc = [&](size_t bytes) {
    char* p = ws + off;
    off += (bytes + 255) & ~(size_t)255;
    return p;
  };
  bf16* xb  = (bf16*)alloc((size_t)BT * DD * 2);       // x bf16 (reused as attn out)
  bf16* Wt  = (bf16*)alloc((size_t)NQKV * DD * 2);     // [wq|wk|wv]^T (reused as q_rope)
  bf16* Wot = (bf16*)alloc((size_t)DD * DD * 2);       // wo^T
  bf16* qkv = (bf16*)alloc((size_t)BT * NQKV * 2);     // fused qkv
  bf16* kro = (bf16*)alloc((size_t)BT * KVH * HDIM * 2);
  bf16* vb  = (bf16*)alloc((size_t)BT * KVH * HDIM * 2);
  bf16* vbt = (bf16*)alloc((size_t)BT * KVH * HDIM * 2);
  bf16* qro = Wt;   // alias: Wt dead after QKV GEMM
  bf16* aob = xb;   // alias: xb dead after QKV GEMM
  (void)ws_size; (void)in_sizes; (void)n_in; (void)out_size;

  cast_bf16_k<<<2048, 256, 0, stream>>>(x, xb, BT * DD / 4);
  transpose_cast_k<<<dim3(2048 / 32, 2048 / 32), 256, 0, stream>>>(wq, Wt, 2048, 2048);
  transpose_cast_k<<<dim3(1024 / 32, 2048 / 32), 256, 0, stream>>>(wk, Wt + (size_t)2048 * 2048, 2048, 1024);
  transpose_cast_k<<<dim3(1024 / 32, 2048 / 32), 256, 0, stream>>>(wv, Wt + (size_t)3072 * 2048, 2048, 1024);
  transpose_cast_k<<<dim3(2048 / 32, 2048 / 32), 256, 0, stream>>>(wo, Wot, 2048, 2048);

  // QKV GEMM: 256^2 8-phase (M=4096, N=4096 -> 256 blocks)
  gemm256_k<0><<<dim3((BT / 256) * (NQKV / 256)), 512, 0, stream>>>(xb, Wt, qkv, BT, NQKV, DD);

  norm_rope_k<<<BT, 256, 0, stream>>>(qkv, qn_w, kn_w, sinb, cosb, qro, kro, vb);
  transpose_v_k<<<dim3(TT / 32, HDIM / 32, BB * KVH), 256, 0, stream>>>(vb, vbt);

  attn4_k<<<dim3(TQ, HH, BB), 512, 0, stream>>>(qro, kro, vbt, aob);

  // out-proj: 256^2 8-phase (M=4096, N=2048 -> 128 blocks)
  gemm256_k<1><<<dim3((BT / 256) * (DD / 256)), 512, 0, stream>>>(aob, Wot, out, BT, DD, DD);
}

// Round 6
// 231.526 us; speedup vs baseline: 1.1893x; 1.0537x over previous
//
#include <hip/hip_runtime.h>
#include <hip/hip_bf16.h>
#include <stdint.h>

// ---------------- problem constants ----------------
#define BB 2
#define TT 2048
#define DD 2048
#define HH 16
#define KVH 8
#define HDIM 128
#define BT (BB*TT)            // 4096
#define NQKV (HH*HDIM + 2*KVH*HDIM) // 4096
#define TQ (TT/128)           // 16 q-blocks of 128 rows
#define ATT_SCALE 0.08838834764831845f
#define RMS_EPS 1e-6f

typedef __bf16 bf16;
typedef __bf16 bf16x8 __attribute__((ext_vector_type(8)));
typedef __bf16 bf16x4 __attribute__((ext_vector_type(4)));
typedef __bf16 bf16x2 __attribute__((ext_vector_type(2)));
typedef float  f32x4  __attribute__((ext_vector_type(4)));
typedef float  f32x16 __attribute__((ext_vector_type(16)));
typedef unsigned u32x4 __attribute__((ext_vector_type(4)));

// async global->LDS, 16B per lane. LDS dest = wave-uniform base + lane*16.
__device__ __forceinline__ void gl_lds16(const void* g, const void* l) {
  __builtin_amdgcn_global_load_lds(
      (const __attribute__((address_space(1))) void*)(uintptr_t)g,
      (__attribute__((address_space(3))) void*)(uint32_t)(uintptr_t)l,
      16, 0, 0);
}

// pack two f32 -> one u32 of 2 bf16 (lo, hi)
__device__ __forceinline__ unsigned pkbf(float lo, float hi) {
  bf16x2 t = { (bf16)lo, (bf16)hi };
  return __builtin_bit_cast(unsigned, t);
}

// ---------------- elementwise f32 -> bf16 cast ----------------
__global__ __launch_bounds__(256) void cast_bf16_k(const float* __restrict__ in,
                                                   bf16* __restrict__ out, int n4) {
  int i = blockIdx.x * blockDim.x + threadIdx.x;
  int stride = gridDim.x * blockDim.x;
  for (; i < n4; i += stride) {
    float4 v = ((const float4*)in)[i];
    bf16x4 o = { (bf16)v.x, (bf16)v.y, (bf16)v.z, (bf16)v.w };
    *(bf16x4*)(out + (size_t)i * 4) = o;
  }
}

// ---------------- f32 (R x C) -> bf16 (C x R) transpose-cast ----------------
__global__ __launch_bounds__(256) void transpose_cast_k(const float* __restrict__ in,
                                                        bf16* __restrict__ out,
                                                        int R, int C) {
  __shared__ float tile[32][33];
  int tx = threadIdx.x & 31, ty = threadIdx.x >> 5;
  int c0 = blockIdx.x * 32, r0 = blockIdx.y * 32;
#pragma unroll
  for (int i = 0; i < 4; ++i)
    tile[ty + 8*i][tx] = in[(size_t)(r0 + ty + 8*i) * C + c0 + tx];
  __syncthreads();
#pragma unroll
  for (int i = 0; i < 4; ++i)
    out[(size_t)(c0 + ty + 8*i) * R + r0 + tx] = (bf16)tile[tx][ty + 8*i];
}

// ---------------- bf16 V transpose: (B,T,KV,HD) -> (B,KV,HD,T) ----------------
__global__ __launch_bounds__(256) void transpose_v_k(const bf16* __restrict__ vb,
                                                     bf16* __restrict__ vbt) {
  __shared__ bf16 tile[32][33];
  int tx = threadIdx.x & 31, ty = threadIdx.x >> 5;
  int t0 = blockIdx.x * 32;
  int d0 = blockIdx.y * 32;
  int bk = blockIdx.z;                 // b*KV + kv
  int b = bk >> 3, kv = bk & 7;
#pragma unroll
  for (int i = 0; i < 4; ++i)
    tile[ty + 8*i][tx] = vb[(((size_t)(b*TT + t0 + ty + 8*i)) * KVH + kv) * HDIM + d0 + tx];
  __syncthreads();
#pragma unroll
  for (int i = 0; i < 4; ++i)
    vbt[(((size_t)bk) * HDIM + d0 + ty + 8*i) * TT + t0 + tx] = tile[tx][ty + 8*i];
}

// ---------------- GEMM 256x256, BK=64, 8-phase counted-vmcnt schedule ----------------
template <int OUT_F32>
__global__ __launch_bounds__(512, 2)
void gemm256_k(const bf16* __restrict__ A, const bf16* __restrict__ Bt,
               void* __restrict__ Cout, int M, int N, int K) {
  __shared__ bf16 S[2 * 2 * 2 * 128 * 64];   // 128 KiB
  const int tid = threadIdx.x, lane = tid & 63, wid = tid >> 6;
  const int lr = lane & 15, lq = lane >> 4;
  const int wrow = wid >> 1, wcol = wid & 1;

  // XCD-aware bijective swizzle of the flat block id (nwg % 8 == 0 here)
  const int nwg = gridDim.x;
  const int o = blockIdx.x;
  const int ns = (o & 7) * (nwg >> 3) + (o >> 3);
  const int GX = N >> 8;
  const int by = ns / GX, bx = ns % GX;

  const int NT = K >> 6;
  const bf16* Ab = A + (size_t)(by * 256) * K;
  const bf16* Bb = Bt + (size_t)(bx * 256) * K;

  const int srow = tid >> 3;
  const size_t soff = (size_t)srow * K + (((tid & 7) ^ (srow & 7)) * 8);
  const int ldst0 = wid * 512;

  auto STAGE = [&](int op, int h, int t_) {
    int tc = t_ < NT ? t_ : NT - 1;
    const bf16* src = (op ? Bb : Ab) + soff + (size_t)(h * 128) * K + tc * 64;
    bf16* dst = S + ((((((t_ & 1) << 1) | op) << 1) | h) << 13) + ldst0;
#pragma unroll
    for (int i = 0; i < 2; ++i)
      gl_lds16(src + (size_t)(i * 64) * K, dst + i * 4096);
  };

  bf16x8 af[2][2][2];   // [mh][m][ks]
  bf16x8 bfr[4][2];     // [n][ks]
  f32x4 acc[4][2][4] = {};  // [quad][m][n]

  auto LOAD_A = [&](int buf) {
#pragma unroll
    for (int mh = 0; mh < 2; ++mh) {
      const bf16* base = S + (((buf << 2) | mh) << 13);
#pragma unroll
      for (int m = 0; m < 2; ++m) {
        int ra = wrow * 32 + m * 16 + lr;
#pragma unroll
        for (int ks = 0; ks < 2; ++ks)
          af[mh][m][ks] = *(const bf16x8*)(base + ra * 64 + (((ks * 4 + lq) ^ (ra & 7)) * 8));
      }
    }
  };
  auto LOAD_B = [&](int buf, int nh) {
    const bf16* base = S + (((buf << 2) | 2 | nh) << 13);
#pragma unroll
    for (int n = 0; n < 4; ++n) {
      int rb = wcol * 64 + n * 16 + lr;
#pragma unroll
      for (int ks = 0; ks < 2; ++ks)
        bfr[n][ks] = *(const bf16x8*)(base + rb * 64 + (((ks * 4 + lq) ^ (rb & 7)) * 8));
    }
  };
  auto MFMA_Q = [&](int qd, int mh) {
#pragma unroll
    for (int m = 0; m < 2; ++m)
#pragma unroll
      for (int n = 0; n < 4; ++n)
#pragma unroll
        for (int ks = 0; ks < 2; ++ks)
          acc[qd][m][n] = __builtin_amdgcn_mfma_f32_16x16x32_bf16(
              af[mh][m][ks], bfr[n][ks], acc[qd][m][n], 0, 0, 0);
  };

  STAGE(0, 0, 0); STAGE(0, 1, 0); STAGE(1, 0, 0); STAGE(1, 1, 0);
  STAGE(0, 0, 1); STAGE(0, 1, 1); STAGE(1, 0, 1);
  asm volatile("s_waitcnt vmcnt(6)" ::: "memory");
  __builtin_amdgcn_sched_barrier(0);
  __builtin_amdgcn_s_barrier();

  for (int t = 0; t < NT; ++t) {
    const int buf = t & 1;
    LOAD_A(buf);
    LOAD_B(buf, 0);
    STAGE(1, 1, t + 1);
    __builtin_amdgcn_s_barrier();
    asm volatile("s_waitcnt lgkmcnt(0)" ::: "memory");
    __builtin_amdgcn_sched_barrier(0);
    __builtin_amdgcn_s_setprio(1);
    MFMA_Q(0, 0);
    __builtin_amdgcn_s_setprio(0);
    __builtin_amdgcn_sched_barrier(0);
    __builtin_amdgcn_s_barrier();
    STAGE(0, 0, t + 2);
    __builtin_amdgcn_s_barrier();
    __builtin_amdgcn_s_setprio(1);
    MFMA_Q(1, 1);
    __builtin_amdgcn_s_setprio(0);
    __builtin_amdgcn_sched_barrier(0);
    __builtin_amdgcn_s_barrier();
    LOAD_B(buf, 1);
    STAGE(0, 1, t + 2);
    __builtin_amdgcn_s_barrier();
    asm volatile("s_waitcnt lgkmcnt(0)" ::: "memory");
    __builtin_amdgcn_sched_barrier(0);
    __builtin_amdgcn_s_setprio(1);
    MFMA_Q(2, 1);
    __builtin_amdgcn_s_setprio(0);
    __builtin_amdgcn_sched_barrier(0);
    __builtin_amdgcn_s_barrier();
    STAGE(1, 0, t + 2);
    asm volatile("s_waitcnt vmcnt(6)" ::: "memory");
    __builtin_amdgcn_sched_barrier(0);
    __builtin_amdgcn_s_barrier();
    __builtin_amdgcn_s_setprio(1);
    MFMA_Q(3, 0);
    __builtin_amdgcn_s_setprio(0);
    __builtin_amdgcn_sched_barrier(0);
    __builtin_amdgcn_s_barrier();
  }

#pragma unroll
  for (int qd = 0; qd < 4; ++qd) {
    const int mh = (qd == 1 || qd == 2) ? 1 : 0;
    const int nh = (qd >= 2) ? 1 : 0;
#pragma unroll
    for (int m = 0; m < 2; ++m)
#pragma unroll
      for (int n = 0; n < 4; ++n)
#pragma unroll
        for (int j = 0; j < 4; ++j) {
          int row = by * 256 + mh * 128 + wrow * 32 + m * 16 + lq * 4 + j;
          int col = bx * 256 + nh * 128 + wcol * 64 + n * 16 + lr;
          if (OUT_F32) ((float*)Cout)[(size_t)row * N + col] = acc[qd][m][n][j];
          else         ((bf16*)Cout)[(size_t)row * N + col] = (bf16)acc[qd][m][n][j];
        }
  }
}

// ---------------- fused RMSNorm + RoPE + split ----------------
__global__ __launch_bounds__(256) void norm_rope_k(const bf16* __restrict__ qkv,
                                                   const float* __restrict__ qn_w,
                                                   const float* __restrict__ kn_w,
                                                   const float* __restrict__ sinb,
                                                   const float* __restrict__ cosb,
                                                   bf16* __restrict__ qro,
                                                   bf16* __restrict__ kro,
                                                   bf16* __restrict__ vo) {
  const int bt = blockIdx.x;
  const int tid = threadIdx.x, lane = tid & 63, wid = tid >> 6;
  const bf16* row = qkv + (size_t)bt * NQKV;
  const float sv = sinb[bt * 64 + lane];
  const float cv = cosb[bt * 64 + lane];
  for (int it = 0; it < 8; ++it) {
    int hv = it * 4 + wid;   // 0..31 : 0-15 q, 16-23 k, 24-31 v
    int off = (hv < 16) ? hv * 128 : (hv < 24) ? 2048 + (hv - 16) * 128 : 3072 + (hv - 24) * 128;
    float e0 = (float)row[off + lane];
    float e1 = (float)row[off + 64 + lane];
    if (hv >= 24) {
      bf16* dst = vo + (size_t)bt * (KVH * HDIM) + (hv - 24) * 128;
      dst[lane] = (bf16)e0;
      dst[64 + lane] = (bf16)e1;
    } else {
      float ss = e0 * e0 + e1 * e1;
#pragma unroll
      for (int o = 32; o >= 1; o >>= 1) ss += __shfl_xor(ss, o, 64);
      float rms = rsqrtf(ss * (1.0f / 128.0f) + RMS_EPS);
      const float* wn = (hv < 16) ? qn_w : kn_w;
      float n0 = e0 * rms * wn[lane];
      float n1 = e1 * rms * wn[lane + 64];
      float o0 = n0 * cv - n1 * sv;
      float o1 = n1 * cv + n0 * sv;
      if (hv < 16) {
        bf16* dst = qro + (size_t)bt * (HH * HDIM) + hv * 128;
        dst[lane] = (bf16)o0; dst[64 + lane] = (bf16)o1;
      } else {
        bf16* dst = kro + (size_t)bt * (KVH * HDIM) + (hv - 16) * 128;
        dst[lane] = (bf16)o0; dst[64 + lane] = (bf16)o1;
      }
    }
  }
}

// ---------------- GQA causal flash attention, v5: swapped QK^T, 32x32 MFMA ----
// grid (TQ=16, H, B); 4 waves (256 thr), each owns 32 q-rows (QBLK=128).
// KVBLK=64. S^T = mfma32(K, Q): lane holds P[q=lane&31][32 kv slots]; softmax
// fully in-register (in-lane reduce + one lane^32 exchange). P packed to bf16
// words in-register; half-exchanges build PV A-fragments (no P LDS).
// K LDS [64][128] 4-bit XOR swizzle; V LDS [128][64] 3-bit swizzle; both give
// optimal 8-lane/bank-quad spread on the 32-row column reads.
__global__ __launch_bounds__(256, 2)
void attn5_k(const bf16* __restrict__ qr, const bf16* __restrict__ kr,
             const bf16* __restrict__ vbt, bf16* __restrict__ ao) {
  __shared__ bf16 Ks[2][64 * 128];
  __shared__ bf16 Vs[2][128 * 64];
  __shared__ float Al[4][32];
  const int tid = threadIdx.x, lane = tid & 63, wid = tid >> 6;
  const int l31 = lane & 31, hi = lane >> 5;
  const int h = blockIdx.y, b = blockIdx.z;
  const int qt = (b & 1) ? (TQ - 1 - blockIdx.x) : blockIdx.x;
  const int kvh = h >> 1;            // N_REP = 2
  const int q0w = qt * 128 + wid * 32;
  const int qg = q0w + l31;          // this lane's q row
  const int nt = 2 * qt + 2;

  auto STAGE = [&](int bufi, int kt) {
#pragma unroll
    for (int i = 0; i < 4; ++i) {
      int u = i * 256 + tid;          // 0..1023
      int krow = u >> 4, kcc = u & 15;
      gl_lds16(&kr[(((size_t)(b * TT + kt * 64 + krow)) * KVH + kvh) * HDIM + ((kcc ^ (krow & 15)) * 8)],
               &Ks[bufi][(i * 256 + wid * 64) * 8]);
      int vrow = u >> 3, vcc = u & 7;
      gl_lds16(&vbt[(((size_t)(b * KVH + kvh)) * HDIM + vrow) * TT + kt * 64 + ((vcc ^ (vrow & 7)) * 8)],
               &Vs[bufi][(i * 256 + wid * 64) * 8]);
    }
  };

  // Q fragments (B-operand): k=(lane>>5)*8+j at k-step ks -> d = ks*16+hi*8+j
  bf16x8 qf[8];
  const bf16* qrow = &qr[(((size_t)(b * TT + qg)) * HH + h) * HDIM];
#pragma unroll
  for (int ks = 0; ks < 8; ++ks)
    qf[ks] = *(const bf16x8*)(qrow + ks * 16 + hi * 8);

  f32x16 accO[4] = {};
  float m = -INFINITY, lsum = 0.f;

  int buf = 0;
  STAGE(0, 0);
  __syncthreads();

  for (int kt = 0; kt < nt; ++kt) {
    if (kt + 1 < nt) STAGE(buf ^ 1, kt + 1);

    if (kt * 64 <= q0w + 31) {   // wave-uniform skip of fully-masked tiles
      const char* Kb = (const char*)&Ks[buf][0];
      const char* Vb = (const char*)&Vs[buf][0];

      // ---- S^T = K Q^T : lane holds S[q=qg][kv = ct*32 + crow(r,hi)] ----
      f32x16 sacc[2];
#pragma unroll
      for (int ct = 0; ct < 2; ++ct) {
#pragma unroll
        for (int j = 0; j < 16; ++j) sacc[ct][j] = 0.f;
        int krow = ct * 32 + l31;
#pragma unroll
        for (int ks = 0; ks < 8; ++ks) {
          bf16x8 kf = *(const bf16x8*)(Kb + krow * 256 + (((2 * ks + hi) ^ (krow & 15)) * 16));
          sacc[ct] = __builtin_amdgcn_mfma_f32_32x32x16_bf16(kf, qf[ks], sacc[ct], 0, 0, 0);
        }
      }

      // ---- mask + scale + in-lane max ----
      const bool domask = (kt * 64 + 63 > q0w);
      float p[2][16];
      float pmx = -INFINITY;
#pragma unroll
      for (int ct = 0; ct < 2; ++ct) {
        int lim = qg - (kt * 64 + ct * 32 + 4 * hi);   // valid iff crow0 <= lim
#pragma unroll
        for (int r = 0; r < 16; ++r) {
          const int crow0 = (r & 3) + 8 * (r >> 2);
          float v = sacc[ct][r] * ATT_SCALE;
          v = (!domask || crow0 <= lim) ? v : -INFINITY;
          p[ct][r] = v;
          pmx = fmaxf(pmx, v);
        }
      }
      pmx = fmaxf(pmx, __shfl_xor(pmx, 32, 64));   // full-row max

      // ---- defer-max (T13) ----
      if (__any(pmx > m + 8.f)) {
        float mnew = fmaxf(m, pmx);
        float alpha = __expf(m - mnew);
        m = mnew;
        lsum *= alpha;
        if (lane < 32) Al[wid][l31] = alpha;
        __builtin_amdgcn_s_waitcnt(0);  // lgkm drain: wave-local LDS visibility
#pragma unroll
        for (int n = 0; n < 4; ++n)
#pragma unroll
          for (int r = 0; r < 16; ++r) {
            const int crow = (r & 3) + 8 * (r >> 2) + 4 * hi;
            accO[n][r] *= Al[wid][crow];
          }
      }

      // ---- P = exp(S - m), in-lane sum ----
      float rsum = 0.f;
#pragma unroll
      for (int ct = 0; ct < 2; ++ct)
#pragma unroll
        for (int r = 0; r < 16; ++r) {
          float e = __expf(p[ct][r] - m);
          p[ct][r] = e;
          rsum += e;
        }
      rsum += __shfl_xor(rsum, 32, 64);
      lsum += rsum;

      // ---- pack P -> PV A-fragments (in-register, half-exchanges) ----
      bf16x8 pa[4];
#pragma unroll
      for (int ct = 0; ct < 2; ++ct) {
        unsigned W[8];
#pragma unroll
        for (int mi = 0; mi < 8; ++mi)
          W[mi] = pkbf(p[ct][2 * mi], p[ct][2 * mi + 1]);
#pragma unroll
        for (int a = 0; a < 2; ++a) {
          unsigned s0 = __shfl_xor(W[4 * a + 0], 32, 64);
          unsigned s1 = __shfl_xor(W[4 * a + 1], 32, 64);
          unsigned s2 = __shfl_xor(W[4 * a + 2], 32, 64);
          unsigned s3 = __shfl_xor(W[4 * a + 3], 32, 64);
          u32x4 wv;
          wv[0] = hi ? s2 : W[4 * a + 0];
          wv[1] = hi ? s3 : W[4 * a + 1];
          wv[2] = hi ? W[4 * a + 2] : s0;
          wv[3] = hi ? W[4 * a + 3] : s1;
          pa[ct * 2 + a] = __builtin_bit_cast(bf16x8, wv);
        }
      }

      // ---- O += P V ----
#pragma unroll
      for (int n = 0; n < 4; ++n) {
        int vrow = n * 32 + l31;
#pragma unroll
        for (int ks = 0; ks < 4; ++ks) {
          bf16x8 vf = *(const bf16x8*)(Vb + vrow * 128 + (((2 * ks + hi) ^ (vrow & 7)) * 16));
          accO[n] = __builtin_amdgcn_mfma_f32_32x32x16_bf16(pa[ks], vf, accO[n], 0, 0, 0);
        }
      }
    }

    __syncthreads();
    buf ^= 1;
  }

  // ---- epilogue: O /= l (transpose 1/l via per-wave LDS slot) ----
  float inv = 1.0f / lsum;
  __syncthreads();                 // reuse of Al safe across earlier rescales
  if (lane < 32) Al[wid][l31] = inv;
  __builtin_amdgcn_s_waitcnt(0);
#pragma unroll
  for (int n = 0; n < 4; ++n)
#pragma unroll
    for (int r = 0; r < 16; ++r) {
      const int crow = (r & 3) + 8 * (r >> 2) + 4 * hi;
      size_t idx = (((size_t)(b * TT + q0w + crow)) * HH + h) * HDIM + n * 32 + l31;
      ao[idx] = (bf16)(accO[n][r] * Al[wid][crow]);
    }
}

// ---------------- launcher ----------------
extern "C" void kernel_launch(void* const* d_in, const int* in_sizes, int n_in,
                              void* d_out, int out_size, void* d_ws, size_t ws_size,
                              hipStream_t stream) {
  const float* x    = (const float*)d_in[0];
  const float* wq   = (const float*)d_in[1];
  const float* wk   = (const float*)d_in[2];
  const float* wv   = (const float*)d_in[3];
  const float* wo   = (const float*)d_in[4];
  const float* qn_w = (const float*)d_in[5];
  const float* kn_w = (const float*)d_in[6];
  const float* sinb = (const float*)d_in[7];
  const float* cosb = (const float*)d_in[8];
  float* out = (float*)d_out;

  char* ws = (char*)d_ws;
  size_t off = 0;
  auto alloc = [&](size_t bytes) {
    char* p = ws + off;
    off += (bytes + 255) & ~(size_t)255;
    return p;
  };
  bf16* xb  = (bf16*)alloc((size_t)BT * DD * 2);       // x bf16 (reused as attn out)
  bf16* Wt  = (bf16*)alloc((size_t)NQKV * DD * 2);     // [wq|wk|wv]^T (reused as q_rope)
  bf16* Wot = (bf16*)alloc((size_t)DD * DD * 2);       // wo^T
  bf16* qkv = (bf16*)alloc((size_t)BT * NQKV * 2);     // fused qkv
  bf16* kro = (bf16*)alloc((size_t)BT * KVH * HDIM * 2);
  bf16* vb  = (bf16*)alloc((size_t)BT * KVH * HDIM * 2);
  bf16* vbt = (bf16*)alloc((size_t)BT * KVH * HDIM * 2);
  bf16* qro = Wt;   // alias: Wt dead after QKV GEMM
  bf16* aob = xb;   // alias: xb dead after QKV GEMM
  (void)ws_size; (void)in_sizes; (void)n_in; (void)out_size;

  cast_bf16_k<<<2048, 256, 0, stream>>>(x, xb, BT * DD / 4);
  transpose_cast_k<<<dim3(2048 / 32, 2048 / 32), 256, 0, stream>>>(wq, Wt, 2048, 2048);
  transpose_cast_k<<<dim3(1024 / 32, 2048 / 32), 256, 0, stream>>>(wk, Wt + (size_t)2048 * 2048, 2048, 1024);
  transpose_cast_k<<<dim3(1024 / 32, 2048 / 32), 256, 0, stream>>>(wv, Wt + (size_t)3072 * 2048, 2048, 1024);
  transpose_cast_k<<<dim3(2048 / 32, 2048 / 32), 256, 0, stream>>>(wo, Wot, 2048, 2048);

  // QKV GEMM: 256^2 8-phase (M=4096, N=4096 -> 256 blocks)
  gemm256_k<0><<<dim3((BT / 256) * (NQKV / 256)), 512, 0, stream>>>(xb, Wt, qkv, BT, NQKV, DD);

  norm_rope_k<<<BT, 256, 0, stream>>>(qkv, qn_w, kn_w, sinb, cosb, qro, kro, vb);
  transpose_v_k<<<dim3(TT / 32, HDIM / 32, BB * KVH), 256, 0, stream>>>(vb, vbt);

  attn5_k<<<dim3(TQ, HH, BB), 256, 0, stream>>>(qro, kro, vbt, aob);

  // out-proj: 256^2 8-phase (M=4096, N=2048 -> 128 blocks)
  gemm256_k<1><<<dim3((BT / 256) * (DD / 256)), 512, 0, stream>>>(aob, Wot, out, BT, DD, DD);
}